// Round 14
// baseline (15473.680 us; speedup 1.0000x reference)
//
#include <hip/hip_runtime.h>
#include <math.h>

#define NDIM 4096
#define NR   4095        // rounds = N-1 (rotating positions)
#define NPAIRS 2048      // N/2 tables
#define CB   8           // columns per workgroup slice
#define NTHREADS 256
#define NWAVES (NTHREADS / 64)   // 4
#define TPT  8           // tables per thread (NPAIRS / NTHREADS)

// Precompute (c, s) per (round, table); bake in the orientation sign:
// table k at round r holds players a=(r+k)%NR (top) and b=(r-k)%NR (bottom,
// or 4095 fixed for k=0). Reference rotates (i,j)=(min,max) with
// U[i]=c*Ui-s*Uj, U[j]=s*Ui+c*Uj. If top==j negate s. top>bottom iff 0<k<=r<NR-k.
__global__ void cs_precompute(const float* __restrict__ thetas,
                              const int* __restrict__ round_theta,
                              float2* __restrict__ cs, int total) {
    int idx = blockIdx.x * blockDim.x + threadIdx.x;
    if (idx >= total) return;
    int r = idx / NPAIRS;
    int k = idx - r * NPAIRS;
    float th = thetas[round_theta[idx]];
    float s, c;
    sincosf(th, &s, &c);
    if (k > 0 && k <= r && r < NR - k) s = -s;
    cs[idx] = make_float2(c, s);
}

// Register-systolic circle method + LAGGED cross-wave exchange (r14).
// r0-r10: same-round exchange = [export write -> lgkm drain -> barrier ->
// read -> merge] serialized every round; measured per-round wall gap
// ~1250cy at 2 streams/SIMD (r8/r10), and r10 proved the vmcnt drain is
// not the cause. r14: boundary lanes compute their own imports:
//   t7(lane63) = c*top0_nbr(r) - s*prevNbL   [top0_nbr from LDS, 1 rd old]
//   bi(lane0)  = s*prevNa0 + c*bot7_nbr(r)   [bot7_nbr from LDS, 1 rd old]
// identities hold because the neighbor's boundary-table influx IS our own
// previous-round export (kept in registers). LDS read at round TOP hits
// data written last round (no same-round dependency); barrier only gates
// slot reuse. Values are bit-identical to the old protocol.
// PIN rules (r7/r8/r9): input-only "v" pins on T/B each phase MANDATORY
// (SROA + VGPR residence + schedule fence), no tied-def copy tax; never
// cap launch bounds below live-set. XBAR (r10): lgkmcnt-only barrier
// keeps cs prefetch in flight across rounds.
#define XBAR()                                                          \
  { asm volatile("s_waitcnt lgkmcnt(0)" ::: "memory");                  \
    __builtin_amdgcn_s_barrier(); }

#define PIN8(A, U)                                                      \
    asm volatile("" :: "v"(A[U][0]), "v"(A[U][1]), "v"(A[U][2]),        \
                       "v"(A[U][3]), "v"(A[U][4]), "v"(A[U][5]),        \
                       "v"(A[U][6]), "v"(A[U][7]))

#define PINALL()                                                        \
  { PIN8(T, 0); PIN8(T, 1); PIN8(T, 2); PIN8(T, 3);                     \
    PIN8(T, 4); PIN8(T, 5); PIN8(T, 6); PIN8(T, 7);                     \
    PIN8(B, 0); PIN8(B, 1); PIN8(B, 2); PIN8(B, 3);                     \
    PIN8(B, 4); PIN8(B, 5); PIN8(B, 6); PIN8(B, 7); }

// In-place rotation of table U at phase P (both na and nb stay renamed).
#define UPD(U, P, CC, SS)                                                     \
  { const float c_ = (CC), s_ = (SS);                                         \
    _Pragma("unroll") for (int c = 0; c < CB; ++c) {                          \
      float a = T[((U) + (P)) & 7][c], b = B[((U) - (P) + 8) & 7][c];         \
      T[((U) + (P)) & 7][c] = fmaf(c_, a, -(s_ * b));                         \
      B[((U) - (P) + 8) & 7][c] = fmaf(s_, a, c_ * b); } }

// One round at phase P. BUF = this round's cs (float4[4]); DO_PF: prefetch
// BUF <- round RND+2. DO_PH: prefetch boundary cs (hcs) <- round RND+1.
#define PHASE(P, RND, BUF, DO_PF, DO_PH)                                      \
  {                                                                           \
    PINALL();                                                                 \
    float hst[CB];  /* lane63: nbr top0 | lane0: nbr bot7 (1 round old) */    \
    if (lane == 63 && wave < NWAVES - 1) {                                    \
      _Pragma("unroll") for (int c = 0; c < CB; ++c)                          \
        hst[c] = naS[(RND) & 1][wave + 1][c]; }                               \
    if (lane == 0 && wave > 0) {                                              \
      _Pragma("unroll") for (int c = 0; c < CB; ++c)                          \
        hst[c] = nbS[(RND) & 1][wave - 1][c]; }                               \
    float na0[CB], nb0[CB], nbL[CB];                                          \
    { /* u=0: na exported left, nb deferred (tid==0 turnaround) */            \
      const float c_ = BUF[0].x, s_ = BUF[0].y;                               \
      _Pragma("unroll") for (int c = 0; c < CB; ++c) {                        \
        float a = T[(P) & 7][c], b = B[(0 - (P) + 8) & 7][c];                 \
        na0[c] = fmaf(c_, a, -(s_ * b));                                      \
        nb0[c] = fmaf(s_, a, c_ * b); } }                                     \
    { /* u=7 early: na in place, nb exported right */                         \
      const float c_ = BUF[3].z, s_ = BUF[3].w;                               \
      _Pragma("unroll") for (int c = 0; c < CB; ++c) {                        \
        float a = T[(7 + (P)) & 7][c], b = B[(7 - (P) + 8) & 7][c];           \
        T[(7 + (P)) & 7][c] = fmaf(c_, a, -(s_ * b));                         \
        nbL[c] = fmaf(s_, a, c_ * b); } }                                     \
    float t7[CB], bi[CB];                                                     \
    _Pragma("unroll") for (int c = 0; c < CB; ++c) {                          \
      t7[c] = __shfl_down(na0[c], 1);                                         \
      bi[c] = __shfl_up(nbL[c], 1); }                                         \
    if (lane == 63) { /* lagged cross-wave top import */                      \
      _Pragma("unroll") for (int c = 0; c < CB; ++c)                          \
        t7[c] = (wave == NWAVES - 1) ? nbL[c]                                 \
                : fmaf(hcs.x, hst[c], -(hcs.y * prevX[c])); }                 \
    if (lane == 0 && wave > 0) { /* lagged cross-wave bot import */           \
      _Pragma("unroll") for (int c = 0; c < CB; ++c)                          \
        bi[c] = fmaf(hcs.y, prevX[c], hcs.x * hst[c]); }                      \
    UPD(1, P, BUF[0].z, BUF[0].w)                                             \
    UPD(2, P, BUF[1].x, BUF[1].y)                                             \
    UPD(3, P, BUF[1].z, BUF[1].w)                                             \
    UPD(4, P, BUF[2].x, BUF[2].y)                                             \
    UPD(5, P, BUF[2].z, BUF[2].w)                                             \
    UPD(6, P, BUF[3].x, BUF[3].y)                                             \
    if (DO_PF) { /* after last BUF read: used at round RND+2 */               \
      const float4* pf_ = csp + (size_t)((RND) + 2) * (NPAIRS / 2);           \
      BUF[0] = pf_[0]; BUF[1] = pf_[1]; BUF[2] = pf_[2]; BUF[3] = pf_[3];     \
    }                                                                         \
    float2 hn;                                                                \
    if (DO_PH) { if (lane == 0 || lane == 63)                                 \
        hn = cs2[(size_t)((RND) + 1) * NPAIRS + hidx]; }                      \
    _Pragma("unroll") for (int c = 0; c < CB; ++c)                            \
      prevX[c] = (lane == 0) ? na0[c] : nbL[c];                               \
    _Pragma("unroll") for (int c = 0; c < CB; ++c) {                          \
      T[(P) & 7][c] = t7[c];                       /* top import slot */      \
      B[(0 - (P) + 8) & 7][c] = (tid == 0) ? na0[c] : nb0[c];                 \
      B[(7 - (P) + 8) & 7][c] = (tid == 0) ? nb0[c] : bi[c];                  \
    }                                                                         \
    if (lane == 0) { /* export post-round top_0 (set at u=1) */               \
      _Pragma("unroll") for (int c = 0; c < CB; ++c)                          \
        naS[((RND) + 1) & 1][wave][c] = T[(1 + (P)) & 7][c]; }                \
    if (lane == 63) { /* export post-round bot_7 (set at u=6) */              \
      _Pragma("unroll") for (int c = 0; c < CB; ++c)                          \
        nbS[((RND) + 1) & 1][wave][c] = B[(6 - (P) + 8) & 7][c]; }            \
    if (DO_PH) hcs = hn;                                                      \
    XBAR();                                                                   \
  }

__global__ __launch_bounds__(NTHREADS, 2)
void rotmat_systolic(const float2* __restrict__ cs,
                     float* __restrict__ out) {
    __shared__ float naS[2][NWAVES][CB];
    __shared__ float nbS[2][NWAVES][CB];

    const int tid  = threadIdx.x;
    const int lane = tid & 63;
    const int wave = tid >> 6;
    const int col0 = blockIdx.x * CB;

    float T[TPT][CB], B[TPT][CB];
    // phase 0: top[u] -> T[u] (row g = tid*8+u), bot[u] -> B[u] (row 4095-g)
#pragma unroll
    for (int u = 0; u < TPT; ++u) {
        int g = tid * TPT + u;
        int rowB = NR - g;            // g=0 -> 4095 (fixed player)
#pragma unroll
        for (int c = 0; c < CB; ++c) {
            T[u][c] = (g == col0 + c) ? 1.f : 0.f;
            B[u][c] = (rowB == col0 + c) ? 1.f : 0.f;
        }
    }

    // cs as float4: round r, thread quads at csp + r*1024 + {0..3}
    const float4* csp = (const float4*)cs + (size_t)tid * (TPT / 2);
    const float2* cs2 = cs;
    float4 csbE[4], csbO[4];
    { const float4* p = csp;                                   // round 0
      csbE[0] = p[0]; csbE[1] = p[1]; csbE[2] = p[2]; csbE[3] = p[3]; }
    { const float4* p = csp + (size_t)1 * (NPAIRS / 2);        // round 1
      csbO[0] = p[0]; csbO[1] = p[1]; csbO[2] = p[2]; csbO[3] = p[3]; }

    // boundary cs index: lane63 -> next wave's first table; lane0 -> left
    // neighbor's last table. Clamped at global ends (values unused there).
    const int hidx = (lane == 63)
        ? ((tid + 1) * TPT < NPAIRS ? (tid + 1) * TPT : NPAIRS - 1)
        : (tid * TPT - 1 > 0 ? tid * TPT - 1 : 0);
    float2 hcs;
    if (lane == 0 || lane == 63) hcs = cs2[hidx];      // round 0

    // prevX: lane63 = bot of neighbor table k0 entering round 0 (initial
    // identity row NR-k0); lane0 = top of left-neighbor last table kL
    // entering round 0 (identity row kL). Others unused.
    float prevX[CB];
    {
        int rowPrev = (lane == 63) ? (NR - (tid + 1) * TPT) : (tid * TPT - 1);
#pragma unroll
        for (int c = 0; c < CB; ++c)
            prevX[c] = (rowPrev == col0 + c) ? 1.f : 0.f;
    }
    // seed LDS slot 0 with initial boundary state (read at round 0)
    if (lane == 0) {
#pragma unroll
        for (int c = 0; c < CB; ++c) naS[0][wave][c] = T[0][c];
    }
    if (lane == 63) {
#pragma unroll
        for (int c = 0; c < CB; ++c) nbS[0][wave][c] = B[7][c];
    }
    __syncthreads();

    int r = 0;
    for (int it = 0; it < 511; ++it, r += 8) {   // rounds 0..4087
        PHASE(0, r,     csbE, 1, 1)
        PHASE(1, r + 1, csbO, 1, 1)
        PHASE(2, r + 2, csbE, 1, 1)
        PHASE(3, r + 3, csbO, 1, 1)
        PHASE(4, r + 4, csbE, 1, 1)
        PHASE(5, r + 5, csbO, 1, 1)
        PHASE(6, r + 6, csbE, 1, 1)
        PHASE(7, r + 7, csbO, 1, 1)
    }
    // tail: rounds 4088..4094 (phases 0..6). Last BUF prefetch at P4
    // (round 4094); last hcs prefetch at P5 (round 4094).
    PHASE(0, r,     csbE, 1, 1)
    PHASE(1, r + 1, csbO, 1, 1)
    PHASE(2, r + 2, csbE, 1, 1)
    PHASE(3, r + 3, csbO, 1, 1)
    PHASE(4, r + 4, csbE, 1, 1)
    PHASE(5, r + 5, csbO, 0, 1)
    PHASE(6, r + 6, csbE, 0, 0)

    // final phase index Q = NR mod 8 = 7:
    // top[u] -> T[(u+7)&7], bot[u] -> B[(u-7)&7] = B[(u+1)&7]
#pragma unroll
    for (int u = 0; u < TPT; ++u) {
        int g = tid * TPT + u;
        int rowB = NR - g;
        float* Tp = T[(u + 7) & 7];
        float* Bp = B[(u + 1) & 7];
        float4* oT = (float4*)&out[(size_t)g * NDIM + col0];
        oT[0] = make_float4(Tp[0], Tp[1], Tp[2], Tp[3]);
        oT[1] = make_float4(Tp[4], Tp[5], Tp[6], Tp[7]);
        float4* oB = (float4*)&out[(size_t)rowB * NDIM + col0];
        oB[0] = make_float4(Bp[0], Bp[1], Bp[2], Bp[3]);
        oB[1] = make_float4(Bp[4], Bp[5], Bp[6], Bp[7]);
    }
}

extern "C" void kernel_launch(void* const* d_in, const int* in_sizes, int n_in,
                              void* d_out, int out_size, void* d_ws, size_t ws_size,
                              hipStream_t stream) {
    const float* thetas      = (const float*)d_in[0];
    const int*   round_theta = (const int*)d_in[3];
    float*       out         = (float*)d_out;

    const int total = NR * NPAIRS;
    float2* cs = (float2*)d_ws;   // 67 MB workspace (verified sufficient)

    cs_precompute<<<(total + 255) / 256, 256, 0, stream>>>(
        thetas, round_theta, cs, total);
    rotmat_systolic<<<NDIM / CB, NTHREADS, 0, stream>>>(cs, out);
}